// Round 10
// baseline (255.774 us; speedup 1.0000x reference)
//
#include <hip/hip_runtime.h>
#include <hip/hip_bf16.h>

// RNN-T Joiner. N=8 T=512 U=64 J=512 V=500 (padded 512).
// ws: enc_p bf16 [4096,512] | dec_p bf16 [512,512] | wimg bf16 frag-ordered (512KB) | bpad
// prep (273 blocks): conv_wout (128) | enc proj (128) | dec proj (16) | bpad (1)
// joiner: persistent, grid 256 x 512 thr (1 block/CU), 16 t-tiles per block.
//   Per tile: BM=64, BN=512, BK=32, 8 waves across V, mfma 32x32x16, B global->regs.
//   Tile-level pipeline: stores of tile i-1 spread across tile i's k-loop (8KB NT chunk
//   per kt); ALL barriers are lgkmcnt-only raw s_barrier -> stores never drain at barriers.
//   LDS: A dbuf 8KB + ep [64][516] f32 132KB = 140KB.

typedef __attribute__((ext_vector_type(4))) float f32x4;
typedef __attribute__((ext_vector_type(16))) float f32x16;
typedef __attribute__((ext_vector_type(4))) short s16x4;
typedef __attribute__((ext_vector_type(8))) short s16x8;
typedef __attribute__((ext_vector_type(4))) unsigned short u16x4;

static __device__ __forceinline__ unsigned short f2bf(float x) {
    union { float f; unsigned u; } v; v.f = x;
    return (unsigned short)((v.u + 0x7FFFu + ((v.u >> 16) & 1u)) >> 16);  // RNE
}

static __device__ __forceinline__ float bf2f(unsigned short u) {
    union { unsigned u; float f; } v; v.u = ((unsigned)u) << 16;
    return v.f;
}

static __device__ __forceinline__ float fast_tanh(float x) {
    float e = __expf(2.0f * x);
    float r = __builtin_amdgcn_rcpf(e + 1.0f);
    return __builtin_fmaf(-2.0f, r, 1.0f);
}

// lgkm-only barrier: orders LDS cross-wave, does NOT drain global NT stores.
static __device__ __forceinline__ void lbar() {
    asm volatile("s_waitcnt lgkmcnt(0)" ::: "memory");
    __builtin_amdgcn_s_barrier();
    __builtin_amdgcn_sched_barrier(0);
}

// 64B-row swizzle: row r, 16B-slot c; byte = r*64 + ((c ^ ((r>>1)&3)) << 4)
static __device__ __forceinline__ unsigned swz64(int r, int c) {
    return (unsigned)(r * 64 + ((c ^ ((r >> 1) & 3)) << 4));
}

// ---------------- projection GEMM body (verified; bf16 output) ----------------
static __device__ void proj_body(
    const float* __restrict__ A, const float* __restrict__ W,
    const float* __restrict__ b, unsigned short* __restrict__ C,
    int mt, int jt, unsigned short* As, unsigned short* Bs)
{
    const int tid = threadIdx.x;
    const int lane = tid & 63, wid = tid >> 6;
    const int wm = wid >> 1, wn = wid & 1;

    f32x4 acc[4][4];
    const f32x4 zero = {0.f, 0.f, 0.f, 0.f};
    #pragma unroll
    for (int i = 0; i < 4; ++i)
        #pragma unroll
        for (int j = 0; j < 4; ++j) acc[i][j] = zero;

    const int c8 = (tid & 7) * 8;
    const int rbase = tid >> 3;

    for (int kt = 0; kt < 8; ++kt) {
        __syncthreads();
        #pragma unroll
        for (int p = 0; p < 4; ++p) {
            int r = p * 32 + rbase;
            int byte = (r * 128 + c8 * 2) ^ ((r & 7) << 4);
            {
                const float* s = A + (size_t)(mt * 128 + r) * 512 + kt * 64 + c8;
                f32x4 v0 = *(const f32x4*)s, v1 = *(const f32x4*)(s + 4);
                s16x8 pk;
                pk[0] = (short)f2bf(v0[0]); pk[1] = (short)f2bf(v0[1]);
                pk[2] = (short)f2bf(v0[2]); pk[3] = (short)f2bf(v0[3]);
                pk[4] = (short)f2bf(v1[0]); pk[5] = (short)f2bf(v1[1]);
                pk[6] = (short)f2bf(v1[2]); pk[7] = (short)f2bf(v1[3]);
                *(s16x8*)((char*)As + byte) = pk;
            }
            {
                const float* s = W + (size_t)(jt * 128 + r) * 512 + kt * 64 + c8;
                f32x4 v0 = *(const f32x4*)s, v1 = *(const f32x4*)(s + 4);
                s16x8 pk;
                pk[0] = (short)f2bf(v0[0]); pk[1] = (short)f2bf(v0[1]);
                pk[2] = (short)f2bf(v0[2]); pk[3] = (short)f2bf(v0[3]);
                pk[4] = (short)f2bf(v1[0]); pk[5] = (short)f2bf(v1[1]);
                pk[6] = (short)f2bf(v1[2]); pk[7] = (short)f2bf(v1[3]);
                *(s16x8*)((char*)Bs + byte) = pk;
            }
        }
        __syncthreads();
        #pragma unroll
        for (int kk = 0; kk < 2; ++kk) {
            s16x8 af[4], bfr[4];
            #pragma unroll
            for (int mi = 0; mi < 4; ++mi) {
                int row = wm * 64 + mi * 16 + (lane & 15);
                int byte = (row * 128 + kk * 64 + ((lane >> 4) * 16)) ^ ((row & 7) << 4);
                af[mi] = *(const s16x8*)((const char*)As + byte);
            }
            #pragma unroll
            for (int ni = 0; ni < 4; ++ni) {
                int row = wn * 64 + ni * 16 + (lane & 15);
                int byte = (row * 128 + kk * 64 + ((lane >> 4) * 16)) ^ ((row & 7) << 4);
                bfr[ni] = *(const s16x8*)((const char*)Bs + byte);
            }
            #pragma unroll
            for (int mi = 0; mi < 4; ++mi)
                #pragma unroll
                for (int ni = 0; ni < 4; ++ni)
                    acc[mi][ni] = __builtin_amdgcn_mfma_f32_16x16x32_bf16(
                        af[mi], bfr[ni], acc[mi][ni], 0, 0, 0);
        }
    }

    #pragma unroll
    for (int ni = 0; ni < 4; ++ni) {
        int col = jt * 128 + wn * 64 + ni * 16 + (lane & 15);
        float bias = b[col];
        #pragma unroll
        for (int mi = 0; mi < 4; ++mi) {
            int row0 = mt * 128 + wm * 64 + mi * 16 + ((lane >> 4) << 2);
            #pragma unroll
            for (int j = 0; j < 4; ++j)
                C[(size_t)(row0 + j) * 512 + col] = f2bf(acc[mi][ni][j] + bias);
        }
    }
}

// ---------------- fused prep: conv_wout | enc proj | dec proj | bpad ----------------
__global__ __launch_bounds__(256) void prep(
    const float* __restrict__ Wout, unsigned short* __restrict__ img,
    const float* __restrict__ encoder_out, const float* __restrict__ W_enc,
    const float* __restrict__ b_enc, unsigned short* __restrict__ enc_p,
    const float* __restrict__ decoder_out, const float* __restrict__ W_dec,
    const float* __restrict__ b_dec, unsigned short* __restrict__ dec_p,
    const float* __restrict__ b_out, float* __restrict__ bpad)
{
    __shared__ unsigned short As[128 * 64];
    __shared__ unsigned short Bs[128 * 64];
    const int b = blockIdx.x;
    if (b < 128) {
        // W_out -> bf16 per-lane MFMA-fragment-ordered image (verified layout):
        // chunk tid = ((kt*16+tile)*2+khalf)*64+lane -> 8 bf16 of
        //   W[v=tile*32+(lane&31)][k=kt*32+khalf*16+(lane>>5)*8 + j], v>=500 -> 0
        int tid = b * 256 + threadIdx.x;
        int lane = tid & 63;
        int khalf = (tid >> 6) & 1;
        int tile = (tid >> 7) & 15;
        int kt = tid >> 11;
        int v = tile * 32 + (lane & 31);
        int k = kt * 32 + khalf * 16 + (lane >> 5) * 8;
        s16x8 pk = {0, 0, 0, 0, 0, 0, 0, 0};
        if (v < 500) {
            const float* s = Wout + (size_t)v * 512 + k;
            f32x4 a = *(const f32x4*)s, c = *(const f32x4*)(s + 4);
            pk[0] = (short)f2bf(a[0]); pk[1] = (short)f2bf(a[1]);
            pk[2] = (short)f2bf(a[2]); pk[3] = (short)f2bf(a[3]);
            pk[4] = (short)f2bf(c[0]); pk[5] = (short)f2bf(c[1]);
            pk[6] = (short)f2bf(c[2]); pk[7] = (short)f2bf(c[3]);
        }
        *(s16x8*)(img + (size_t)tid * 8) = pk;
    } else if (b < 256) {
        int q = b - 128;                       // enc proj: M=4096
        proj_body(encoder_out, W_enc, b_enc, enc_p, q & 31, q >> 5, As, Bs);
    } else if (b < 272) {
        int q = b - 256;                       // dec proj: M=512
        proj_body(decoder_out, W_dec, b_dec, dec_p, q & 3, q >> 2, As, Bs);
    } else {
        int i = threadIdx.x;                   // bpad: 512-padded bias
        bpad[i] = (i < 500) ? b_out[i] : 0.f;
        bpad[i + 256] = (i + 256 < 500) ? b_out[i + 256] : 0.f;
    }
}

// ---------------- fused tanh + vocab GEMM (persistent, store-pipelined) ----------------
__global__ __launch_bounds__(512, 2) void joiner_main(
    const unsigned short* __restrict__ enc, const unsigned short* __restrict__ dec,
    const unsigned short* __restrict__ Wimg, const float* __restrict__ bout,
    float* __restrict__ out)
{
    __shared__ __align__(16) char raw[8192 + 64 * 516 * 4];   // 140288 B
    unsigned short* As0 = (unsigned short*)raw;               // [64 r][32 k] swizzled
    unsigned short* As1 = (unsigned short*)(raw + 4096);
    float* ep = (float*)(raw + 8192);                         // [64][516] f32

    const int bid = blockIdx.x;                 // 0..255
    const int tid = threadIdx.x, lane = tid & 63, wn = tid >> 6;  // 8 waves across V
    const int n = bid >> 5;                     // 32 blocks per n
    const int t0 = (bid & 31) * 16;             // 16 consecutive t per block

    // A staging coords: thread -> row r = tid>>3 (u), 8B chunk q (k = q*4..+3)
    const int r = tid >> 3;
    const int q = tid & 7;
    const unsigned short* drow = dec + ((size_t)n * 64 + r) * 512 + q * 4;
    const unsigned abyte = swz64(r, q >> 1) + (q & 1) * 8;
    // B frags: global frag-ordered image; wave wn owns v-tiles wn*2+{0,1}
    const char* wbase = (const char*)Wimg + (size_t)wn * 4096 + (size_t)lane * 16;
    const int lr = lane & 31, kg = lane >> 5;
    const int hi4 = (lane >> 5) * 4;

    const unsigned short* erow0 = enc + ((size_t)n * 512 + t0) * 512 + q * 4;

    f32x16 acc[2][2];

    // ---- prologue tile 0: stage A(kt0), prefetch e/d(kt1) ----
    u16x4 e0, d0;
    {
        u16x4 e = *(const u16x4*)erow0;
        u16x4 d = *(const u16x4*)drow;
        s16x4 p;
        p[0] = (short)f2bf(fast_tanh(bf2f(e[0]) + bf2f(d[0])));
        p[1] = (short)f2bf(fast_tanh(bf2f(e[1]) + bf2f(d[1])));
        p[2] = (short)f2bf(fast_tanh(bf2f(e[2]) + bf2f(d[2])));
        p[3] = (short)f2bf(fast_tanh(bf2f(e[3]) + bf2f(d[3])));
        *(s16x4*)((char*)As0 + abyte) = p;
        e0 = *(const u16x4*)(erow0 + 32);
        d0 = *(const u16x4*)(drow + 32);
    }
    lbar();

    for (int it = 0; it < 16; ++it) {
        const unsigned short* erow = erow0 + (size_t)it * 512;
        const size_t pslab = (((size_t)n * 512 + t0 + it - 1) * 64) * 500;  // tile it-1

        #pragma unroll
        for (int i = 0; i < 2; ++i)
            #pragma unroll
            for (int j = 0; j < 2; ++j)
                #pragma unroll
                for (int el = 0; el < 16; ++el) acc[i][j][el] = 0.f;

        // ---- k-loop: compute tile it, stream out tile it-1 ----
        #pragma unroll 2
        for (int kt = 0; kt < 16; ++kt) {
            const char* Ac = (char*)((kt & 1) ? As1 : As0);
            char* An = (char*)((kt & 1) ? As0 : As1);

            // 1. B fragment loads for this kt (oldest vmem in FIFO this iteration)
            const char* g = wbase + (size_t)kt * 32768;
            s16x8 b00 = *(const s16x8*)(g);
            s16x8 b0k = *(const s16x8*)(g + 1024);
            s16x8 b10 = *(const s16x8*)(g + 2048);
            s16x8 b1k = *(const s16x8*)(g + 3072);
            // 2. store-spread: one contiguous 8KB NT chunk of tile it-1
            if (it > 0 && tid < 500) {
                int idx = kt * 500 + tid;
                int rr = idx / 125;
                int vi = (idx - rr * 125) * 4;
                f32x4 ov = *(const f32x4*)(ep + rr * 516 + vi);
                __builtin_nontemporal_store(ov, (f32x4*)(out + pslab + (size_t)idx * 4));
            }
            // 3. A fragment reads (LDS)
            s16x8 a0k0 = *(const s16x8*)(Ac + swz64(lr, kg));
            s16x8 a1k0 = *(const s16x8*)(Ac + swz64(32 + lr, kg));
            s16x8 a0k1 = *(const s16x8*)(Ac + swz64(lr, 2 + kg));
            s16x8 a1k1 = *(const s16x8*)(Ac + swz64(32 + lr, 2 + kg));
            // 4. stage A(kt+1) from prefetched regs; prefetch e/d(kt+2)
            if (kt < 15) {
                s16x4 p;
                p[0] = (short)f2bf(fast_tanh(bf2f(e0[0]) + bf2f(d0[0])));
                p[1] = (short)f2bf(fast_tanh(bf2f(e0[1]) + bf2f(d0[1])));
                p[2] = (short)f2bf(fast_tanh(bf2f(e0[2]) + bf2f(d0[2])));
                p[3] = (short)f2bf(fast_tanh(bf2f(e0[3]) + bf2f(d0[3])));
                *(s16x4*)(An + abyte) = p;
                if (kt < 14) {
                    e0 = *(const u16x4*)(erow + (kt + 2) * 32);
                    d0 = *(const u16x4*)(drow + (kt + 2) * 32);
                }
            }
            // 5. MFMA (swapped operands: D cols = m, rows = v)
            acc[0][0] = __builtin_amdgcn_mfma_f32_32x32x16_bf16(b00, a0k0, acc[0][0], 0, 0, 0);
            acc[0][1] = __builtin_amdgcn_mfma_f32_32x32x16_bf16(b10, a0k0, acc[0][1], 0, 0, 0);
            acc[1][0] = __builtin_amdgcn_mfma_f32_32x32x16_bf16(b00, a1k0, acc[1][0], 0, 0, 0);
            acc[1][1] = __builtin_amdgcn_mfma_f32_32x32x16_bf16(b10, a1k0, acc[1][1], 0, 0, 0);
            acc[0][0] = __builtin_amdgcn_mfma_f32_32x32x16_bf16(b0k, a0k1, acc[0][0], 0, 0, 0);
            acc[0][1] = __builtin_amdgcn_mfma_f32_32x32x16_bf16(b1k, a0k1, acc[0][1], 0, 0, 0);
            acc[1][0] = __builtin_amdgcn_mfma_f32_32x32x16_bf16(b0k, a1k1, acc[1][0], 0, 0, 0);
            acc[1][1] = __builtin_amdgcn_mfma_f32_32x32x16_bf16(b1k, a1k1, acc[1][1], 0, 0, 0);
            lbar();
        }

        // ---- next-tile kt0/kt1 e/d loads (issued early, used after transpose) ----
        u16x4 en, dn;
        if (it < 15) {
            en = *(const u16x4*)(erow + 512);        // tile it+1, kt0
            dn = *(const u16x4*)drow;
            e0 = *(const u16x4*)(erow + 512 + 32);   // tile it+1, kt1
            d0 = *(const u16x4*)(drow + 32);
        }
        // ---- transpose acc -> ep (with bias); rows m = mi*32+lr ----
        // acc[mi][ni][reg]: v = wn*64 + ni*32 + (reg&3) + 8*(reg>>2) + 4*(lane>>5)
        #pragma unroll
        for (int mi = 0; mi < 2; ++mi) {
            #pragma unroll
            for (int ni = 0; ni < 2; ++ni) {
                #pragma unroll
                for (int qq = 0; qq < 4; ++qq) {
                    int v4 = wn * 64 + ni * 32 + qq * 8 + hi4;
                    if (v4 < 500) {
                        f32x4 b = *(const f32x4*)(bout + v4);   // bout 512-padded
                        f32x4 ov;
                        ov[0] = acc[mi][ni][qq * 4 + 0] + b[0];
                        ov[1] = acc[mi][ni][qq * 4 + 1] + b[1];
                        ov[2] = acc[mi][ni][qq * 4 + 2] + b[2];
                        ov[3] = acc[mi][ni][qq * 4 + 3] + b[3];
                        *(f32x4*)(ep + (mi * 32 + lr) * 516 + v4) = ov;
                    }
                }
            }
        }
        // ---- stage A(kt0) of next tile into As0 ----
        if (it < 15) {
            s16x4 p;
            p[0] = (short)f2bf(fast_tanh(bf2f(en[0]) + bf2f(dn[0])));
            p[1] = (short)f2bf(fast_tanh(bf2f(en[1]) + bf2f(dn[1])));
            p[2] = (short)f2bf(fast_tanh(bf2f(en[2]) + bf2f(dn[2])));
            p[3] = (short)f2bf(fast_tanh(bf2f(en[3]) + bf2f(dn[3])));
            *(s16x4*)((char*)As0 + abyte) = p;
        }
        lbar();
    }

    // ---- final drain: stream out tile 15 ----
    {
        const size_t slab = (((size_t)n * 512 + t0 + 15) * 64) * 500;
        #pragma unroll
        for (int kt = 0; kt < 16; ++kt) {
            if (tid < 500) {
                int idx = kt * 500 + tid;
                int rr = idx / 125;
                int vi = (idx - rr * 125) * 4;
                f32x4 ov = *(const f32x4*)(ep + rr * 516 + vi);
                __builtin_nontemporal_store(ov, (f32x4*)(out + slab + (size_t)idx * 4));
            }
        }
    }
}

extern "C" void kernel_launch(void* const* d_in, const int* in_sizes, int n_in,
                              void* d_out, int out_size, void* d_ws, size_t ws_size,
                              hipStream_t stream) {
    const float* encoder_out = (const float*)d_in[0];  // [8,512,512]
    const float* decoder_out = (const float*)d_in[1];  // [8,64,512]
    const float* W_enc = (const float*)d_in[2];
    const float* b_enc = (const float*)d_in[3];
    const float* W_dec = (const float*)d_in[4];
    const float* b_dec = (const float*)d_in[5];
    const float* W_out = (const float*)d_in[6];        // [500,512]
    const float* b_out = (const float*)d_in[7];        // [500]
    float* out = (float*)d_out;                        // [8,512,64,500]

    unsigned short* enc_p = (unsigned short*)d_ws;              // 4 MB bf16
    unsigned short* dec_p = enc_p + (size_t)4096 * 512;         // 512 KB bf16
    unsigned short* wimg  = dec_p + (size_t)512 * 512;          // 512 KB bf16
    float* bpad = (float*)(wimg + 262144);                      // 2 KB f32

    prep<<<dim3(273), 256, 0, stream>>>(W_out, wimg,
                                        encoder_out, W_enc, b_enc, enc_p,
                                        decoder_out, W_dec, b_dec, dec_p,
                                        b_out, bpad);
    joiner_main<<<dim3(256), 512, 0, stream>>>(enc_p, dec_p, wimg, bpad, out);
}

// Round 11
// 219.536 us; speedup vs baseline: 1.1651x; 1.1651x over previous
//
#include <hip/hip_runtime.h>
#include <hip/hip_bf16.h>

// RNN-T Joiner. N=8 T=512 U=64 J=512 V=500 (padded 512).
// ws: enc_p bf16 [4096,512] | dec_p bf16 [512,512] | wimg bf16 frag-ordered (512KB) | bpad
// prep (273 blocks): conv_wout (128) | enc proj (128) | dec proj (16) | bpad (1)
// joiner (R8 structure + lgkm-only barriers + reg pipelines):
//   512 thr / 8 waves, BM=64, BN=512, BK=32, wave 64m x 64v, mfma 32x32x16.
//   B(kt+1) and e/d(kt+2) register-prefetched; barriers never drain vmcnt ->
//   global loads and NT stores stay in flight across barriers. 2 blocks/CU.

typedef __attribute__((ext_vector_type(4))) float f32x4;
typedef __attribute__((ext_vector_type(16))) float f32x16;
typedef __attribute__((ext_vector_type(4))) short s16x4;
typedef __attribute__((ext_vector_type(8))) short s16x8;
typedef __attribute__((ext_vector_type(4))) unsigned short u16x4;

static __device__ __forceinline__ unsigned short f2bf(float x) {
    union { float f; unsigned u; } v; v.f = x;
    return (unsigned short)((v.u + 0x7FFFu + ((v.u >> 16) & 1u)) >> 16);  // RNE
}

static __device__ __forceinline__ float bf2f(unsigned short u) {
    union { unsigned u; float f; } v; v.u = ((unsigned)u) << 16;
    return v.f;
}

static __device__ __forceinline__ float fast_tanh(float x) {
    float e = __expf(2.0f * x);
    float r = __builtin_amdgcn_rcpf(e + 1.0f);
    return __builtin_fmaf(-2.0f, r, 1.0f);
}

// lgkm-only barrier (R10-verified correct): orders LDS cross-wave, does NOT
// drain global loads/stores -> B/ed prefetch and NT stores live across it.
static __device__ __forceinline__ void lbar() {
    asm volatile("s_waitcnt lgkmcnt(0)" ::: "memory");
    __builtin_amdgcn_s_barrier();
    __builtin_amdgcn_sched_barrier(0);
}

// 64B-row swizzle: row r, 16B-slot c; byte = r*64 + ((c ^ ((r>>1)&3)) << 4)
static __device__ __forceinline__ unsigned swz64(int r, int c) {
    return (unsigned)(r * 64 + ((c ^ ((r >> 1) & 3)) << 4));
}

// ---------------- projection GEMM body (verified; bf16 output) ----------------
static __device__ void proj_body(
    const float* __restrict__ A, const float* __restrict__ W,
    const float* __restrict__ b, unsigned short* __restrict__ C,
    int mt, int jt, unsigned short* As, unsigned short* Bs)
{
    const int tid = threadIdx.x;
    const int lane = tid & 63, wid = tid >> 6;
    const int wm = wid >> 1, wn = wid & 1;

    f32x4 acc[4][4];
    const f32x4 zero = {0.f, 0.f, 0.f, 0.f};
    #pragma unroll
    for (int i = 0; i < 4; ++i)
        #pragma unroll
        for (int j = 0; j < 4; ++j) acc[i][j] = zero;

    const int c8 = (tid & 7) * 8;
    const int rbase = tid >> 3;

    for (int kt = 0; kt < 8; ++kt) {
        __syncthreads();
        #pragma unroll
        for (int p = 0; p < 4; ++p) {
            int r = p * 32 + rbase;
            int byte = (r * 128 + c8 * 2) ^ ((r & 7) << 4);
            {
                const float* s = A + (size_t)(mt * 128 + r) * 512 + kt * 64 + c8;
                f32x4 v0 = *(const f32x4*)s, v1 = *(const f32x4*)(s + 4);
                s16x8 pk;
                pk[0] = (short)f2bf(v0[0]); pk[1] = (short)f2bf(v0[1]);
                pk[2] = (short)f2bf(v0[2]); pk[3] = (short)f2bf(v0[3]);
                pk[4] = (short)f2bf(v1[0]); pk[5] = (short)f2bf(v1[1]);
                pk[6] = (short)f2bf(v1[2]); pk[7] = (short)f2bf(v1[3]);
                *(s16x8*)((char*)As + byte) = pk;
            }
            {
                const float* s = W + (size_t)(jt * 128 + r) * 512 + kt * 64 + c8;
                f32x4 v0 = *(const f32x4*)s, v1 = *(const f32x4*)(s + 4);
                s16x8 pk;
                pk[0] = (short)f2bf(v0[0]); pk[1] = (short)f2bf(v0[1]);
                pk[2] = (short)f2bf(v0[2]); pk[3] = (short)f2bf(v0[3]);
                pk[4] = (short)f2bf(v1[0]); pk[5] = (short)f2bf(v1[1]);
                pk[6] = (short)f2bf(v1[2]); pk[7] = (short)f2bf(v1[3]);
                *(s16x8*)((char*)Bs + byte) = pk;
            }
        }
        __syncthreads();
        #pragma unroll
        for (int kk = 0; kk < 2; ++kk) {
            s16x8 af[4], bfr[4];
            #pragma unroll
            for (int mi = 0; mi < 4; ++mi) {
                int row = wm * 64 + mi * 16 + (lane & 15);
                int byte = (row * 128 + kk * 64 + ((lane >> 4) * 16)) ^ ((row & 7) << 4);
                af[mi] = *(const s16x8*)((const char*)As + byte);
            }
            #pragma unroll
            for (int ni = 0; ni < 4; ++ni) {
                int row = wn * 64 + ni * 16 + (lane & 15);
                int byte = (row * 128 + kk * 64 + ((lane >> 4) * 16)) ^ ((row & 7) << 4);
                bfr[ni] = *(const s16x8*)((const char*)Bs + byte);
            }
            #pragma unroll
            for (int mi = 0; mi < 4; ++mi)
                #pragma unroll
                for (int ni = 0; ni < 4; ++ni)
                    acc[mi][ni] = __builtin_amdgcn_mfma_f32_16x16x32_bf16(
                        af[mi], bfr[ni], acc[mi][ni], 0, 0, 0);
        }
    }

    #pragma unroll
    for (int ni = 0; ni < 4; ++ni) {
        int col = jt * 128 + wn * 64 + ni * 16 + (lane & 15);
        float bias = b[col];
        #pragma unroll
        for (int mi = 0; mi < 4; ++mi) {
            int row0 = mt * 128 + wm * 64 + mi * 16 + ((lane >> 4) << 2);
            #pragma unroll
            for (int j = 0; j < 4; ++j)
                C[(size_t)(row0 + j) * 512 + col] = f2bf(acc[mi][ni][j] + bias);
        }
    }
}

// ---------------- fused prep: conv_wout | enc proj | dec proj | bpad ----------------
__global__ __launch_bounds__(256) void prep(
    const float* __restrict__ Wout, unsigned short* __restrict__ img,
    const float* __restrict__ encoder_out, const float* __restrict__ W_enc,
    const float* __restrict__ b_enc, unsigned short* __restrict__ enc_p,
    const float* __restrict__ decoder_out, const float* __restrict__ W_dec,
    const float* __restrict__ b_dec, unsigned short* __restrict__ dec_p,
    const float* __restrict__ b_out, float* __restrict__ bpad)
{
    __shared__ unsigned short As[128 * 64];
    __shared__ unsigned short Bs[128 * 64];
    const int b = blockIdx.x;
    if (b < 128) {
        // W_out -> bf16 per-lane MFMA-fragment-ordered image (verified layout):
        // chunk tid = ((kt*16+tile)*2+khalf)*64+lane -> 8 bf16 of
        //   W[v=tile*32+(lane&31)][k=kt*32+khalf*16+(lane>>5)*8 + j], v>=500 -> 0
        int tid = b * 256 + threadIdx.x;
        int lane = tid & 63;
        int khalf = (tid >> 6) & 1;
        int tile = (tid >> 7) & 15;
        int kt = tid >> 11;
        int v = tile * 32 + (lane & 31);
        int k = kt * 32 + khalf * 16 + (lane >> 5) * 8;
        s16x8 pk = {0, 0, 0, 0, 0, 0, 0, 0};
        if (v < 500) {
            const float* s = Wout + (size_t)v * 512 + k;
            f32x4 a = *(const f32x4*)s, c = *(const f32x4*)(s + 4);
            pk[0] = (short)f2bf(a[0]); pk[1] = (short)f2bf(a[1]);
            pk[2] = (short)f2bf(a[2]); pk[3] = (short)f2bf(a[3]);
            pk[4] = (short)f2bf(c[0]); pk[5] = (short)f2bf(c[1]);
            pk[6] = (short)f2bf(c[2]); pk[7] = (short)f2bf(c[3]);
        }
        *(s16x8*)(img + (size_t)tid * 8) = pk;
    } else if (b < 256) {
        int q = b - 128;                       // enc proj: M=4096
        proj_body(encoder_out, W_enc, b_enc, enc_p, q & 31, q >> 5, As, Bs);
    } else if (b < 272) {
        int q = b - 256;                       // dec proj: M=512
        proj_body(decoder_out, W_dec, b_dec, dec_p, q & 3, q >> 2, As, Bs);
    } else {
        int i = threadIdx.x;                   // bpad: 512-padded bias
        bpad[i] = (i < 500) ? b_out[i] : 0.f;
        bpad[i + 256] = (i + 256 < 500) ? b_out[i + 256] : 0.f;
    }
}

// ---------------- fused tanh + vocab GEMM ----------------
__global__ __launch_bounds__(512, 4) void joiner_main(
    const unsigned short* __restrict__ enc, const unsigned short* __restrict__ dec,
    const unsigned short* __restrict__ Wimg, const float* __restrict__ bout,
    float* __restrict__ out)
{
    __shared__ __align__(16) char raw[66048];             // ep [32][516] f32, aliases A dbuf
    unsigned short* As0 = (unsigned short*)raw;           // 4 KB [64 r][32 k] swizzled
    unsigned short* As1 = (unsigned short*)(raw + 4096);
    float* ep = (float*)raw;

    const int bid = blockIdx.x;                 // bid = n*512 + t
    const int tid = threadIdx.x, lane = tid & 63, wn = tid >> 6;  // 8 waves across V
    const int n = bid >> 9, t = bid & 511;

    f32x16 acc[2][2];
    #pragma unroll
    for (int i = 0; i < 2; ++i)
        #pragma unroll
        for (int j = 0; j < 2; ++j)
            #pragma unroll
            for (int e = 0; e < 16; ++e) acc[i][j][e] = 0.f;

    // A staging: thread -> row r = tid>>3 (u 0..63), 8B chunk q = tid&7 (k = q*4..+3)
    const int r = tid >> 3;
    const int q = tid & 7;
    const unsigned short* erow = enc + ((size_t)n * 512 + t) * 512 + q * 4;
    const unsigned short* drow = dec + ((size_t)n * 64 + r) * 512 + q * 4;
    const unsigned abyte = swz64(r, q >> 1) + (q & 1) * 8;
    // B fragments: global frag-ordered image; wave wn owns v-tiles wn*2+{0,1}
    const char* wbase = (const char*)Wimg + (size_t)wn * 4096 + (size_t)lane * 16;
    const int lr = lane & 31, kg = lane >> 5;

    // ---- prologue: stage A(kt0); prefetch e/d(kt1) and B(kt0) into regs ----
    u16x4 eN, dN;
    s16x8 bc0, bc1, bc2, bc3;
    {
        u16x4 e = *(const u16x4*)erow;
        u16x4 d = *(const u16x4*)drow;
        s16x4 p;
        p[0] = (short)f2bf(fast_tanh(bf2f(e[0]) + bf2f(d[0])));
        p[1] = (short)f2bf(fast_tanh(bf2f(e[1]) + bf2f(d[1])));
        p[2] = (short)f2bf(fast_tanh(bf2f(e[2]) + bf2f(d[2])));
        p[3] = (short)f2bf(fast_tanh(bf2f(e[3]) + bf2f(d[3])));
        *(s16x4*)((char*)As0 + abyte) = p;
        eN = *(const u16x4*)(erow + 32);
        dN = *(const u16x4*)(drow + 32);
        bc0 = *(const s16x8*)(wbase);
        bc1 = *(const s16x8*)(wbase + 1024);
        bc2 = *(const s16x8*)(wbase + 2048);
        bc3 = *(const s16x8*)(wbase + 3072);
    }
    lbar();

    #pragma unroll
    for (int kt = 0; kt < 16; ++kt) {
        const char* Ac = (char*)((kt & 1) ? As1 : As0);
        char* An = (char*)((kt & 1) ? As0 : As1);

        // 1. stage A(kt+1) from prefetched regs (no load wait)
        if (kt < 15) {
            s16x4 p;
            p[0] = (short)f2bf(fast_tanh(bf2f(eN[0]) + bf2f(dN[0])));
            p[1] = (short)f2bf(fast_tanh(bf2f(eN[1]) + bf2f(dN[1])));
            p[2] = (short)f2bf(fast_tanh(bf2f(eN[2]) + bf2f(dN[2])));
            p[3] = (short)f2bf(fast_tanh(bf2f(eN[3]) + bf2f(dN[3])));
            *(s16x4*)(An + abyte) = p;
        }
        // 2. prefetch e/d for kt+2 (issued before B so tanh's wait keeps B in flight)
        if (kt < 14) {
            eN = *(const u16x4*)(erow + (kt + 2) * 32);
            dN = *(const u16x4*)(drow + (kt + 2) * 32);
        }
        // 3. prefetch B(kt+1) into regs (latency hidden by this kt's MFMAs)
        s16x8 bn0, bn1, bn2, bn3;
        if (kt < 15) {
            const char* g = wbase + (size_t)(kt + 1) * 32768;
            bn0 = *(const s16x8*)(g);
            bn1 = *(const s16x8*)(g + 1024);
            bn2 = *(const s16x8*)(g + 2048);
            bn3 = *(const s16x8*)(g + 3072);
        }
        // 4. per-kh A fragment reads + MFMA with current B regs
        {
            s16x8 a0 = *(const s16x8*)(Ac + swz64(lr, kg));
            s16x8 a1 = *(const s16x8*)(Ac + swz64(32 + lr, kg));
            acc[0][0] = __builtin_amdgcn_mfma_f32_32x32x16_bf16(bc0, a0, acc[0][0], 0, 0, 0);
            acc[0][1] = __builtin_amdgcn_mfma_f32_32x32x16_bf16(bc2, a0, acc[0][1], 0, 0, 0);
            acc[1][0] = __builtin_amdgcn_mfma_f32_32x32x16_bf16(bc0, a1, acc[1][0], 0, 0, 0);
            acc[1][1] = __builtin_amdgcn_mfma_f32_32x32x16_bf16(bc2, a1, acc[1][1], 0, 0, 0);
        }
        {
            s16x8 a0 = *(const s16x8*)(Ac + swz64(lr, 2 + kg));
            s16x8 a1 = *(const s16x8*)(Ac + swz64(32 + lr, 2 + kg));
            acc[0][0] = __builtin_amdgcn_mfma_f32_32x32x16_bf16(bc1, a0, acc[0][0], 0, 0, 0);
            acc[0][1] = __builtin_amdgcn_mfma_f32_32x32x16_bf16(bc3, a0, acc[0][1], 0, 0, 0);
            acc[1][0] = __builtin_amdgcn_mfma_f32_32x32x16_bf16(bc1, a1, acc[1][0], 0, 0, 0);
            acc[1][1] = __builtin_amdgcn_mfma_f32_32x32x16_bf16(bc3, a1, acc[1][1], 0, 0, 0);
        }
        // 5. lgkm-only barrier (A dbuf hazard); B/ed loads stay in flight
        lbar();
        bc0 = bn0; bc1 = bn1; bc2 = bn2; bc3 = bn3;
    }

    // ---- epilogue: 2 rounds of 32 rows; LDS transpose -> linear NT streams ----
    // acc[mi][ni][reg]: m = mi*32 + (lane&31),
    //                   v = wn*64 + ni*32 + (reg&3) + 8*(reg>>2) + 4*(lane>>5)
    const int hi4 = (lane >> 5) * 4;
    #pragma unroll
    for (int o = 0; o < 2; ++o) {
        if (o) lbar();                    // round 0 covered by k-loop's final lbar
        {
            const int mi = o;
            #pragma unroll
            for (int ni = 0; ni < 2; ++ni) {
                #pragma unroll
                for (int qq = 0; qq < 4; ++qq) {
                    int v4 = wn * 64 + ni * 32 + qq * 8 + hi4;
                    if (v4 < 500) {
                        f32x4 b = *(const f32x4*)(bout + v4);   // bout 512-padded
                        f32x4 ov;
                        ov[0] = acc[mi][ni][qq * 4 + 0] + b[0];
                        ov[1] = acc[mi][ni][qq * 4 + 1] + b[1];
                        ov[2] = acc[mi][ni][qq * 4 + 2] + b[2];
                        ov[3] = acc[mi][ni][qq * 4 + 3] + b[3];
                        *(f32x4*)(ep + lr * 516 + v4) = ov;
                    }
                }
            }
        }
        lbar();
        const size_t obase = ((size_t)bid * 64 + o * 32) * 500;
        #pragma unroll
        for (int i = 0; i < 8; ++i) {
            int idx = i * 512 + tid;                    // f32x4 chunk, 4000 total
            if (idx < 4000) {
                int rr = idx / 125;
                int vi = (idx - rr * 125) * 4;
                f32x4 ov = *(const f32x4*)(ep + rr * 516 + vi);
                __builtin_nontemporal_store(ov, (f32x4*)(out + obase + (size_t)idx * 4));
            }
        }
    }
}

extern "C" void kernel_launch(void* const* d_in, const int* in_sizes, int n_in,
                              void* d_out, int out_size, void* d_ws, size_t ws_size,
                              hipStream_t stream) {
    const float* encoder_out = (const float*)d_in[0];  // [8,512,512]
    const float* decoder_out = (const float*)d_in[1];  // [8,64,512]
    const float* W_enc = (const float*)d_in[2];
    const float* b_enc = (const float*)d_in[3];
    const float* W_dec = (const float*)d_in[4];
    const float* b_dec = (const float*)d_in[5];
    const float* W_out = (const float*)d_in[6];        // [500,512]
    const float* b_out = (const float*)d_in[7];        // [500]
    float* out = (float*)d_out;                        // [8,512,64,500]

    unsigned short* enc_p = (unsigned short*)d_ws;              // 4 MB bf16
    unsigned short* dec_p = enc_p + (size_t)4096 * 512;         // 512 KB bf16
    unsigned short* wimg  = dec_p + (size_t)512 * 512;          // 512 KB bf16
    float* bpad = (float*)(wimg + 262144);                      // 2 KB f32

    prep<<<dim3(273), 256, 0, stream>>>(W_out, wimg,
                                        encoder_out, W_enc, b_enc, enc_p,
                                        decoder_out, W_dec, b_dec, dec_p,
                                        b_out, bpad);
    joiner_main<<<dim3(4096), 512, 0, stream>>>(enc_p, dec_p, wimg, bpad, out);
}

// Round 12
// 219.223 us; speedup vs baseline: 1.1667x; 1.0014x over previous
//
#include <hip/hip_runtime.h>
#include <hip/hip_bf16.h>

// RNN-T Joiner. N=8 T=512 U=64 J=512 V=500 (padded 512).
// ws: enc_p bf16 [4096,512] | dec_p bf16 [512,512] | wimg bf16 frag-ordered (512KB) | bpad
// prep (273 blocks): conv_wout (128) | enc proj (128) | dec proj (16) | bpad (1)
// joiner (R11 + 2-kt barrier intervals):
//   512 thr / 8 waves, BM=64, BN=512, BK=32, wave 64m x 64v, mfma 32x32x16.
//   A in 4x4KB LDS ring staged 2 kt ahead; ONE lgkm-only barrier per 2 kt (8 total).
//   B(kt+1) reg-prefetched; e/d prefetched one interval (2 kt) ahead. 2 blocks/CU.

typedef __attribute__((ext_vector_type(4))) float f32x4;
typedef __attribute__((ext_vector_type(16))) float f32x16;
typedef __attribute__((ext_vector_type(4))) short s16x4;
typedef __attribute__((ext_vector_type(8))) short s16x8;
typedef __attribute__((ext_vector_type(4))) unsigned short u16x4;

static __device__ __forceinline__ unsigned short f2bf(float x) {
    union { float f; unsigned u; } v; v.f = x;
    return (unsigned short)((v.u + 0x7FFFu + ((v.u >> 16) & 1u)) >> 16);  // RNE
}

static __device__ __forceinline__ float bf2f(unsigned short u) {
    union { unsigned u; float f; } v; v.u = ((unsigned)u) << 16;
    return v.f;
}

static __device__ __forceinline__ float fast_tanh(float x) {
    float e = __expf(2.0f * x);
    float r = __builtin_amdgcn_rcpf(e + 1.0f);
    return __builtin_fmaf(-2.0f, r, 1.0f);
}

// lgkm-only barrier (R10/R11-verified): orders LDS cross-wave, never drains vmcnt.
static __device__ __forceinline__ void lbar() {
    asm volatile("s_waitcnt lgkmcnt(0)" ::: "memory");
    __builtin_amdgcn_s_barrier();
    __builtin_amdgcn_sched_barrier(0);
}

// 64B-row swizzle: row r, 16B-slot c; byte = r*64 + ((c ^ ((r>>1)&3)) << 4)
static __device__ __forceinline__ unsigned swz64(int r, int c) {
    return (unsigned)(r * 64 + ((c ^ ((r >> 1) & 3)) << 4));
}

// ---------------- projection GEMM body (verified; bf16 output) ----------------
static __device__ void proj_body(
    const float* __restrict__ A, const float* __restrict__ W,
    const float* __restrict__ b, unsigned short* __restrict__ C,
    int mt, int jt, unsigned short* As, unsigned short* Bs)
{
    const int tid = threadIdx.x;
    const int lane = tid & 63, wid = tid >> 6;
    const int wm = wid >> 1, wn = wid & 1;

    f32x4 acc[4][4];
    const f32x4 zero = {0.f, 0.f, 0.f, 0.f};
    #pragma unroll
    for (int i = 0; i < 4; ++i)
        #pragma unroll
        for (int j = 0; j < 4; ++j) acc[i][j] = zero;

    const int c8 = (tid & 7) * 8;
    const int rbase = tid >> 3;

    for (int kt = 0; kt < 8; ++kt) {
        __syncthreads();
        #pragma unroll
        for (int p = 0; p < 4; ++p) {
            int r = p * 32 + rbase;
            int byte = (r * 128 + c8 * 2) ^ ((r & 7) << 4);
            {
                const float* s = A + (size_t)(mt * 128 + r) * 512 + kt * 64 + c8;
                f32x4 v0 = *(const f32x4*)s, v1 = *(const f32x4*)(s + 4);
                s16x8 pk;
                pk[0] = (short)f2bf(v0[0]); pk[1] = (short)f2bf(v0[1]);
                pk[2] = (short)f2bf(v0[2]); pk[3] = (short)f2bf(v0[3]);
                pk[4] = (short)f2bf(v1[0]); pk[5] = (short)f2bf(v1[1]);
                pk[6] = (short)f2bf(v1[2]); pk[7] = (short)f2bf(v1[3]);
                *(s16x8*)((char*)As + byte) = pk;
            }
            {
                const float* s = W + (size_t)(jt * 128 + r) * 512 + kt * 64 + c8;
                f32x4 v0 = *(const f32x4*)s, v1 = *(const f32x4*)(s + 4);
                s16x8 pk;
                pk[0] = (short)f2bf(v0[0]); pk[1] = (short)f2bf(v0[1]);
                pk[2] = (short)f2bf(v0[2]); pk[3] = (short)f2bf(v0[3]);
                pk[4] = (short)f2bf(v1[0]); pk[5] = (short)f2bf(v1[1]);
                pk[6] = (short)f2bf(v1[2]); pk[7] = (short)f2bf(v1[3]);
                *(s16x8*)((char*)Bs + byte) = pk;
            }
        }
        __syncthreads();
        #pragma unroll
        for (int kk = 0; kk < 2; ++kk) {
            s16x8 af[4], bfr[4];
            #pragma unroll
            for (int mi = 0; mi < 4; ++mi) {
                int row = wm * 64 + mi * 16 + (lane & 15);
                int byte = (row * 128 + kk * 64 + ((lane >> 4) * 16)) ^ ((row & 7) << 4);
                af[mi] = *(const s16x8*)((const char*)As + byte);
            }
            #pragma unroll
            for (int ni = 0; ni < 4; ++ni) {
                int row = wn * 64 + ni * 16 + (lane & 15);
                int byte = (row * 128 + kk * 64 + ((lane >> 4) * 16)) ^ ((row & 7) << 4);
                bfr[ni] = *(const s16x8*)((const char*)Bs + byte);
            }
            #pragma unroll
            for (int mi = 0; mi < 4; ++mi)
                #pragma unroll
                for (int ni = 0; ni < 4; ++ni)
                    acc[mi][ni] = __builtin_amdgcn_mfma_f32_16x16x32_bf16(
                        af[mi], bfr[ni], acc[mi][ni], 0, 0, 0);
        }
    }

    #pragma unroll
    for (int ni = 0; ni < 4; ++ni) {
        int col = jt * 128 + wn * 64 + ni * 16 + (lane & 15);
        float bias = b[col];
        #pragma unroll
        for (int mi = 0; mi < 4; ++mi) {
            int row0 = mt * 128 + wm * 64 + mi * 16 + ((lane >> 4) << 2);
            #pragma unroll
            for (int j = 0; j < 4; ++j)
                C[(size_t)(row0 + j) * 512 + col] = f2bf(acc[mi][ni][j] + bias);
        }
    }
}

// ---------------- fused prep: conv_wout | enc proj | dec proj | bpad ----------------
__global__ __launch_bounds__(256) void prep(
    const float* __restrict__ Wout, unsigned short* __restrict__ img,
    const float* __restrict__ encoder_out, const float* __restrict__ W_enc,
    const float* __restrict__ b_enc, unsigned short* __restrict__ enc_p,
    const float* __restrict__ decoder_out, const float* __restrict__ W_dec,
    const float* __restrict__ b_dec, unsigned short* __restrict__ dec_p,
    const float* __restrict__ b_out, float* __restrict__ bpad)
{
    __shared__ unsigned short As[128 * 64];
    __shared__ unsigned short Bs[128 * 64];
    const int b = blockIdx.x;
    if (b < 128) {
        // W_out -> bf16 per-lane MFMA-fragment-ordered image (verified layout):
        // chunk tid = ((kt*16+tile)*2+khalf)*64+lane -> 8 bf16 of
        //   W[v=tile*32+(lane&31)][k=kt*32+khalf*16+(lane>>5)*8 + j], v>=500 -> 0
        int tid = b * 256 + threadIdx.x;
        int lane = tid & 63;
        int khalf = (tid >> 6) & 1;
        int tile = (tid >> 7) & 15;
        int kt = tid >> 11;
        int v = tile * 32 + (lane & 31);
        int k = kt * 32 + khalf * 16 + (lane >> 5) * 8;
        s16x8 pk = {0, 0, 0, 0, 0, 0, 0, 0};
        if (v < 500) {
            const float* s = Wout + (size_t)v * 512 + k;
            f32x4 a = *(const f32x4*)s, c = *(const f32x4*)(s + 4);
            pk[0] = (short)f2bf(a[0]); pk[1] = (short)f2bf(a[1]);
            pk[2] = (short)f2bf(a[2]); pk[3] = (short)f2bf(a[3]);
            pk[4] = (short)f2bf(c[0]); pk[5] = (short)f2bf(c[1]);
            pk[6] = (short)f2bf(c[2]); pk[7] = (short)f2bf(c[3]);
        }
        *(s16x8*)(img + (size_t)tid * 8) = pk;
    } else if (b < 256) {
        int q = b - 128;                       // enc proj: M=4096
        proj_body(encoder_out, W_enc, b_enc, enc_p, q & 31, q >> 5, As, Bs);
    } else if (b < 272) {
        int q = b - 256;                       // dec proj: M=512
        proj_body(decoder_out, W_dec, b_dec, dec_p, q & 3, q >> 2, As, Bs);
    } else {
        int i = threadIdx.x;                   // bpad: 512-padded bias
        bpad[i] = (i < 500) ? b_out[i] : 0.f;
        bpad[i + 256] = (i + 256 < 500) ? b_out[i + 256] : 0.f;
    }
}

// ---------------- fused tanh + vocab GEMM ----------------
__global__ __launch_bounds__(512, 4) void joiner_main(
    const unsigned short* __restrict__ enc, const unsigned short* __restrict__ dec,
    const unsigned short* __restrict__ Wimg, const float* __restrict__ bout,
    float* __restrict__ out)
{
    __shared__ __align__(16) char raw[66048];         // ep [32][516] f32, aliases A ring
    unsigned short* Asr[4] = {                        // 4 x 4KB A ring [64 r][32 k] swizzled
        (unsigned short*)raw, (unsigned short*)(raw + 4096),
        (unsigned short*)(raw + 8192), (unsigned short*)(raw + 12288)};
    float* ep = (float*)raw;

    const int bid = blockIdx.x;                 // bid = n*512 + t
    const int tid = threadIdx.x, lane = tid & 63, wn = tid >> 6;  // 8 waves across V
    const int n = bid >> 9, t = bid & 511;

    f32x16 acc[2][2];
    #pragma unroll
    for (int i = 0; i < 2; ++i)
        #pragma unroll
        for (int j = 0; j < 2; ++j)
            #pragma unroll
            for (int e = 0; e < 16; ++e) acc[i][j][e] = 0.f;

    // A staging: thread -> row r = tid>>3 (u 0..63), 8B chunk q = tid&7 (k = q*4..+3)
    const int r = tid >> 3;
    const int q = tid & 7;
    const unsigned short* erow = enc + ((size_t)n * 512 + t) * 512 + q * 4;
    const unsigned short* drow = dec + ((size_t)n * 64 + r) * 512 + q * 4;
    const unsigned abyte = swz64(r, q >> 1) + (q & 1) * 8;
    // B fragments: global frag-ordered image; wave wn owns v-tiles wn*2+{0,1}
    const char* wbase = (const char*)Wimg + (size_t)wn * 4096 + (size_t)lane * 16;
    const int lr = lane & 31, kg = lane >> 5;

    // staging helper data in regs: e/d for next-interval kts
    u16x4 e0r, d0r, e1r, d1r;
    s16x8 bc0, bc1, bc2, bc3;

    // ---- prologue: stage A(0),A(1); prefetch e/d(2),(3); B(0) ----
    {
        u16x4 e = *(const u16x4*)erow;
        u16x4 d = *(const u16x4*)drow;
        s16x4 p;
        p[0] = (short)f2bf(fast_tanh(bf2f(e[0]) + bf2f(d[0])));
        p[1] = (short)f2bf(fast_tanh(bf2f(e[1]) + bf2f(d[1])));
        p[2] = (short)f2bf(fast_tanh(bf2f(e[2]) + bf2f(d[2])));
        p[3] = (short)f2bf(fast_tanh(bf2f(e[3]) + bf2f(d[3])));
        *(s16x4*)((char*)Asr[0] + abyte) = p;
        e = *(const u16x4*)(erow + 32);
        d = *(const u16x4*)(drow + 32);
        p[0] = (short)f2bf(fast_tanh(bf2f(e[0]) + bf2f(d[0])));
        p[1] = (short)f2bf(fast_tanh(bf2f(e[1]) + bf2f(d[1])));
        p[2] = (short)f2bf(fast_tanh(bf2f(e[2]) + bf2f(d[2])));
        p[3] = (short)f2bf(fast_tanh(bf2f(e[3]) + bf2f(d[3])));
        *(s16x4*)((char*)Asr[1] + abyte) = p;
        e0r = *(const u16x4*)(erow + 2 * 32);
        d0r = *(const u16x4*)(drow + 2 * 32);
        e1r = *(const u16x4*)(erow + 3 * 32);
        d1r = *(const u16x4*)(drow + 3 * 32);
        bc0 = *(const s16x8*)(wbase);
        bc1 = *(const s16x8*)(wbase + 1024);
        bc2 = *(const s16x8*)(wbase + 2048);
        bc3 = *(const s16x8*)(wbase + 3072);
    }
    lbar();

    // ---- main loop: 8 intervals of 2 kt; ONE barrier per interval ----
    #pragma unroll
    for (int j = 0; j < 8; ++j) {
        const int kt0 = 2 * j, kt1 = 2 * j + 1;
        const char* Ac0 = (const char*)Asr[kt0 & 3];
        const char* Ac1 = (const char*)Asr[kt1 & 3];
        char* An0 = (char*)Asr[(kt0 + 2) & 3];
        char* An1 = (char*)Asr[(kt1 + 2) & 3];

        // 1. stage A(kt0+2), A(kt1+2) from prefetched regs
        if (j < 7) {
            s16x4 p;
            p[0] = (short)f2bf(fast_tanh(bf2f(e0r[0]) + bf2f(d0r[0])));
            p[1] = (short)f2bf(fast_tanh(bf2f(e0r[1]) + bf2f(d0r[1])));
            p[2] = (short)f2bf(fast_tanh(bf2f(e0r[2]) + bf2f(d0r[2])));
            p[3] = (short)f2bf(fast_tanh(bf2f(e0r[3]) + bf2f(d0r[3])));
            *(s16x4*)(An0 + abyte) = p;
            p[0] = (short)f2bf(fast_tanh(bf2f(e1r[0]) + bf2f(d1r[0])));
            p[1] = (short)f2bf(fast_tanh(bf2f(e1r[1]) + bf2f(d1r[1])));
            p[2] = (short)f2bf(fast_tanh(bf2f(e1r[2]) + bf2f(d1r[2])));
            p[3] = (short)f2bf(fast_tanh(bf2f(e1r[3]) + bf2f(d1r[3])));
            *(s16x4*)(An1 + abyte) = p;
        }
        // 2. prefetch e/d for interval j+2 (kt0+4, kt1+4)
        if (j < 6) {
            e0r = *(const u16x4*)(erow + (kt0 + 4) * 32);
            d0r = *(const u16x4*)(drow + (kt0 + 4) * 32);
            e1r = *(const u16x4*)(erow + (kt1 + 4) * 32);
            d1r = *(const u16x4*)(drow + (kt1 + 4) * 32);
        }
        // 3. prefetch B(kt1) into regs; MFMA kt0 with bc
        s16x8 bn0, bn1, bn2, bn3;
        {
            const char* g = wbase + (size_t)kt1 * 32768;
            bn0 = *(const s16x8*)(g);
            bn1 = *(const s16x8*)(g + 1024);
            bn2 = *(const s16x8*)(g + 2048);
            bn3 = *(const s16x8*)(g + 3072);
        }
        {
            s16x8 a0 = *(const s16x8*)(Ac0 + swz64(lr, kg));
            s16x8 a1 = *(const s16x8*)(Ac0 + swz64(32 + lr, kg));
            acc[0][0] = __builtin_amdgcn_mfma_f32_32x32x16_bf16(bc0, a0, acc[0][0], 0, 0, 0);
            acc[0][1] = __builtin_amdgcn_mfma_f32_32x32x16_bf16(bc2, a0, acc[0][1], 0, 0, 0);
            acc[1][0] = __builtin_amdgcn_mfma_f32_32x32x16_bf16(bc0, a1, acc[1][0], 0, 0, 0);
            acc[1][1] = __builtin_amdgcn_mfma_f32_32x32x16_bf16(bc2, a1, acc[1][1], 0, 0, 0);
            a0 = *(const s16x8*)(Ac0 + swz64(lr, 2 + kg));
            a1 = *(const s16x8*)(Ac0 + swz64(32 + lr, 2 + kg));
            acc[0][0] = __builtin_amdgcn_mfma_f32_32x32x16_bf16(bc1, a0, acc[0][0], 0, 0, 0);
            acc[0][1] = __builtin_amdgcn_mfma_f32_32x32x16_bf16(bc3, a0, acc[0][1], 0, 0, 0);
            acc[1][0] = __builtin_amdgcn_mfma_f32_32x32x16_bf16(bc1, a1, acc[1][0], 0, 0, 0);
            acc[1][1] = __builtin_amdgcn_mfma_f32_32x32x16_bf16(bc3, a1, acc[1][1], 0, 0, 0);
        }
        // 4. prefetch B(kt0+2) into bc; MFMA kt1 with bn
        if (j < 7) {
            const char* g = wbase + (size_t)(kt0 + 2) * 32768;
            bc0 = *(const s16x8*)(g);
            bc1 = *(const s16x8*)(g + 1024);
            bc2 = *(const s16x8*)(g + 2048);
            bc3 = *(const s16x8*)(g + 3072);
        }
        {
            s16x8 a0 = *(const s16x8*)(Ac1 + swz64(lr, kg));
            s16x8 a1 = *(const s16x8*)(Ac1 + swz64(32 + lr, kg));
            acc[0][0] = __builtin_amdgcn_mfma_f32_32x32x16_bf16(bn0, a0, acc[0][0], 0, 0, 0);
            acc[0][1] = __builtin_amdgcn_mfma_f32_32x32x16_bf16(bn2, a0, acc[0][1], 0, 0, 0);
            acc[1][0] = __builtin_amdgcn_mfma_f32_32x32x16_bf16(bn0, a1, acc[1][0], 0, 0, 0);
            acc[1][1] = __builtin_amdgcn_mfma_f32_32x32x16_bf16(bn2, a1, acc[1][1], 0, 0, 0);
            a0 = *(const s16x8*)(Ac1 + swz64(lr, 2 + kg));
            a1 = *(const s16x8*)(Ac1 + swz64(32 + lr, 2 + kg));
            acc[0][0] = __builtin_amdgcn_mfma_f32_32x32x16_bf16(bn1, a0, acc[0][0], 0, 0, 0);
            acc[0][1] = __builtin_amdgcn_mfma_f32_32x32x16_bf16(bn3, a0, acc[0][1], 0, 0, 0);
            acc[1][0] = __builtin_amdgcn_mfma_f32_32x32x16_bf16(bn1, a1, acc[1][0], 0, 0, 0);
            acc[1][1] = __builtin_amdgcn_mfma_f32_32x32x16_bf16(bn3, a1, acc[1][1], 0, 0, 0);
        }
        // 5. one lgkm-only barrier per interval
        lbar();
    }

    // ---- epilogue: 2 rounds of 32 rows; LDS transpose -> linear NT streams ----
    // acc[mi][ni][reg]: m = mi*32 + (lane&31),
    //                   v = wn*64 + ni*32 + (reg&3) + 8*(reg>>2) + 4*(lane>>5)
    const int hi4 = (lane >> 5) * 4;
    #pragma unroll
    for (int o = 0; o < 2; ++o) {
        if (o) lbar();                    // round 0 covered by k-loop's final lbar
        {
            const int mi = o;
            #pragma unroll
            for (int ni = 0; ni < 2; ++ni) {
                #pragma unroll
                for (int qq = 0; qq < 4; ++qq) {
                    int v4 = wn * 64 + ni * 32 + qq * 8 + hi4;
                    if (v4 < 500) {
                        f32x4 b = *(const f32x4*)(bout + v4);   // bout 512-padded
                        f32x4 ov;
                        ov[0] = acc[mi][ni][qq * 4 + 0] + b[0];
                        ov[1] = acc[mi][ni][qq * 4 + 1] + b[1];
                        ov[2] = acc[mi][ni][qq * 4 + 2] + b[2];
                        ov[3] = acc[mi][ni][qq * 4 + 3] + b[3];
                        *(f32x4*)(ep + lr * 516 + v4) = ov;
                    }
                }
            }
        }
        lbar();
        const size_t obase = ((size_t)bid * 64 + o * 32) * 500;
        #pragma unroll
        for (int i = 0; i < 8; ++i) {
            int idx = i * 512 + tid;                    // f32x4 chunk, 4000 total
            if (idx < 4000) {
                int rr = idx / 125;
                int vi = (idx - rr * 125) * 4;
                f32x4 ov = *(const f32x4*)(ep + rr * 516 + vi);
                __builtin_nontemporal_store(ov, (f32x4*)(out + obase + (size_t)idx * 4));
            }
        }
    }
}

extern "C" void kernel_launch(void* const* d_in, const int* in_sizes, int n_in,
                              void* d_out, int out_size, void* d_ws, size_t ws_size,
                              hipStream_t stream) {
    const float* encoder_out = (const float*)d_in[0];  // [8,512,512]
    const float* decoder_out = (const float*)d_in[1];  // [8,64,512]
    const float* W_enc = (const float*)d_in[2];
    const float* b_enc = (const float*)d_in[3];
    const float* W_dec = (const float*)d_in[4];
    const float* b_dec = (const float*)d_in[5];
    const float* W_out = (const float*)d_in[6];        // [500,512]
    const float* b_out = (const float*)d_in[7];        // [500]
    float* out = (float*)d_out;                        // [8,512,64,500]

    unsigned short* enc_p = (unsigned short*)d_ws;              // 4 MB bf16
    unsigned short* dec_p = enc_p + (size_t)4096 * 512;         // 512 KB bf16
    unsigned short* wimg  = dec_p + (size_t)512 * 512;          // 512 KB bf16
    float* bpad = (float*)(wimg + 262144);                      // 2 KB f32

    prep<<<dim3(273), 256, 0, stream>>>(W_out, wimg,
                                        encoder_out, W_enc, b_enc, enc_p,
                                        decoder_out, W_dec, b_dec, dec_p,
                                        b_out, bpad);
    joiner_main<<<dim3(4096), 512, 0, stream>>>(enc_p, dec_p, wimg, bpad, out);
}